// Round 11
// baseline (378.158 us; speedup 1.0000x reference)
//
#include <hip/hip_runtime.h>
#include <hip/hip_bf16.h>
#include <math.h>

#define B_TOTAL 262144
#define D 16
#define CTX 128
#define H 192
#define IN_DIM 145
#define KP1 160      // layer-1 K: [y(16), t(1), pad(15), h(128)]
#define M 64         // rows per block; 4 waves, each covering all 64 rows x 48 cols
#define BLOCK 256

typedef __attribute__((ext_vector_type(8))) short bf16x8;
typedef __attribute__((ext_vector_type(4))) float f32x4;
typedef __attribute__((ext_vector_type(2))) float f32x2;
typedef __attribute__((ext_vector_type(4))) unsigned short u16x4;
typedef __attribute__((ext_vector_type(2))) __bf16 bf16v2;

// operand-swapped MFMA: computes Z^T = W^T * X^T with the SAME register
// fragments as Z = X*W. Thread owns 4 consecutive columns of one row.
#define MFMA(a, b, c) __builtin_amdgcn_mfma_f32_16x16x32_bf16((a), (b), (c), 0, 0, 0)

__device__ __forceinline__ unsigned short f2bf_rne(float f) {
    unsigned u = __builtin_bit_cast(unsigned, f);
    u += 0x7FFFu + ((u >> 16) & 1u);
    return (unsigned short)(u >> 16);
}
// pair RNE f32->bf16 via fptrunc <2 x float> -> v_cvt_pk_bf16_f32 (RNE, bit-
// identical to f2bf_rne for finite values)
__device__ __forceinline__ unsigned cvtpk(f32x2 v) {
    bf16v2 b = __builtin_convertvector(v, bf16v2);
    return __builtin_bit_cast(unsigned, b);
}
// truncation-based hi/lo split: hi = trunc-bf16(v), lo = RNE(v - hi)
__device__ __forceinline__ void split2(float v, unsigned short& hi, unsigned short& lo) {
    unsigned u = __builtin_bit_cast(unsigned, v);
    hi = (unsigned short)(u >> 16);
    float hf = __builtin_bit_cast(float, u & 0xFFFF0000u);
    lo = f2bf_rne(v - hf);
}
// pair version: packed hi (trunc) and lo (RNE) words
__device__ __forceinline__ void split2x2(f32x2 v, unsigned& hip, unsigned& lop) {
    unsigned ux = __builtin_bit_cast(unsigned, v.x);
    unsigned uy = __builtin_bit_cast(unsigned, v.y);
    hip = (ux >> 16) | (uy & 0xFFFF0000u);
    f32x2 hf;
    hf.x = __builtin_bit_cast(float, ux & 0xFFFF0000u);
    hf.y = __builtin_bit_cast(float, uy & 0xFFFF0000u);
    lop = cvtpk(v - hf);   // v - hf exact in fp32
}
// paired GELU: identical expression trees to the scalar gelu_pair (same
// contraction shapes -> same fp32 results); mul/fma ops packable to v_pk_*
__device__ __forceinline__ void gelu_pair2(f32x2 x, f32x2& a, f32x2& gp) {
    f32x2 s = x * x;
    f32x2 e;
    e.x = __expf(-0.5f * s.x);
    e.y = __expf(-0.5f * s.y);
    f32x2 ax;
    ax.x = fabsf(x.x);
    ax.y = fabsf(x.y);
    f32x2 az = ax * 0.70710678118654752f;
    f32x2 den = 0.3275911f * az + 1.0f;                  // fma, as scalar fmaf
    f32x2 t;
    t.x = __builtin_amdgcn_rcpf(den.x);
    t.y = __builtin_amdgcn_rcpf(den.y);
    f32x2 p = t * (0.254829592f + t * (-0.284496736f + t * (1.421413741f +
              t * (-1.453152027f + t * 1.061405429f))));
    f32x2 er = 1.0f - p * e;                             // contracts like scalar
    f32x2 erfv;
    erfv.x = __builtin_copysignf(er.x, x.x);
    erfv.y = __builtin_copysignf(er.y, x.y);
    f32x2 phi = 0.5f * erfv + 0.5f;                      // fma(0.5, erfv, 0.5)
    gp = (0.39894228040143268f * x) * e + phi;           // mul then fma, as scalar
    a  = x * phi;
}

// ---------- pre-kernel: weights -> [N][K] bf16 in d_ws ----------
// Wt1: [192][160] @0 (k' map: 0-15->y rows, 16->t row(144), 17-31->0, 32+i->h row 16+i)
// Wt2: [192][192] @30720 ; Wt3: [16][192] @67584
__global__ void prep_weights(const float* __restrict__ W1,
                             const float* __restrict__ W2,
                             const float* __restrict__ W3,
                             unsigned short* __restrict__ wt)
{
    int i = blockIdx.x * 256 + threadIdx.x;
    if (i < H * KP1) {
        int n = i / KP1, kp = i % KP1;
        float v = 0.0f;
        if (kp < 16)       v = W1[kp * H + n];
        else if (kp == 16) v = W1[144 * H + n];
        else if (kp >= 32) v = W1[(kp - 16) * H + n];
        wt[i] = f2bf_rne(v);
        return;
    }
    i -= H * KP1;
    if (i < H * H) {
        int n = i / H, k = i % H;
        wt[30720 + i] = f2bf_rne(W2[k * H + n]);
        return;
    }
    i -= H * H;
    if (i < D * H) {
        int n = i / H, k = i % H;
        wt[67584 + i] = f2bf_rne(W3[k * D + n]);
    }
}

// ---------- main kernel: 4 waves, each with 12 independent acc chains ----------
__global__ __launch_bounds__(BLOCK, 3) void odefunc_mfma(
    const float* __restrict__ t_ptr,
    const float* __restrict__ y,
    const float* __restrict__ h,
    const float* __restrict__ eps,
    const float* __restrict__ b1,
    const float* __restrict__ b2,
    const float* __restrict__ b3,
    const unsigned short* __restrict__ wt,
    float* __restrict__ out_f,
    float* __restrict__ out_dlogp,
    float* __restrict__ out_dh)
{
    // Aliased LDS union for 64 rows: staging {Xh 21504 + Xl/Th/Tl 3x5120 = 36864}
    // dead after L1 reads; A/U {2 x 25600 = 51200} alias it. 51200 B -> 3 blk/CU.
    __shared__ __align__(16) unsigned char smem[51200];
    unsigned short (*Xh)[168] = (unsigned short (*)[168])(smem);          // 21504 B
    unsigned short (*Xl)[40]  = (unsigned short (*)[40])(smem + 21504);   //  5120 B
    unsigned short (*Th)[40]  = (unsigned short (*)[40])(smem + 26624);   //  5120 B
    unsigned short (*Tl)[40]  = (unsigned short (*)[40])(smem + 31744);   //  5120 B
    unsigned short (*A)[200]  = (unsigned short (*)[200])(smem);          // 25600 B (alias)
    unsigned short (*U)[200]  = (unsigned short (*)[200])(smem + 25600);  // 25600 B (alias)

    const int tid  = threadIdx.x;
    const int lane = tid & 63;
    const int wv   = tid >> 6;       // 0..3 (column-group; 48 cols each)
    const int quad = lane >> 4;
    const int l16  = lane & 15;
    const size_t r0 = (size_t)blockIdx.x * M;

    const unsigned short* Wt1 = wt;
    const unsigned short* Wt2 = wt + 30720;
    const unsigned short* Wt3 = wt + 67584;

    // ------- zero dh slice (stores only; no dependence) -------
    {
        float4 z4 = {0.f, 0.f, 0.f, 0.f};
        #pragma unroll
        for (int i = 0; i < 8; ++i) {
            int idx = tid + i * BLOCK;            // 2048 float4 = 64 rows x 32
            int r = idx >> 5, c4 = (idx & 31) * 4;
            *(float4*)(out_dh + (r0 + r) * CTX + c4) = z4;
        }
    }

    // ------------- stage inputs (straight-line; paired converts) -------------
    {
        int r = tid >> 2, d4 = (tid & 3) * 4;     // 256 threads = 64 rows x 4 float4
        float4 vy = *(const float4*)(y   + (r0 + r) * D + d4);
        float4 ve = *(const float4*)(eps + (r0 + r) * D + d4);
        unsigned h01, h23, l01, l23;
        f32x2 v01 = { vy.x, vy.y }, v23 = { vy.z, vy.w };
        split2x2(v01, h01, l01); split2x2(v23, h23, l23);
        *(uint2*)&Xh[r][d4] = (uint2){ h01, h23 };
        *(uint2*)&Xl[r][d4] = (uint2){ l01, l23 };
        v01 = (f32x2){ ve.x, ve.y }; v23 = (f32x2){ ve.z, ve.w };
        split2x2(v01, h01, l01); split2x2(v23, h23, l23);
        *(uint2*)&Th[r][d4] = (uint2){ h01, h23 };
        *(uint2*)&Tl[r][d4] = (uint2){ l01, l23 };
    }
    if (tid < M) {      // t column + pads (cols 16..31)
        int r = tid;
        float tv = t_ptr[0];
        unsigned short thi, tlo;
        split2(tv, thi, tlo);
        ushort4 z4 = {0, 0, 0, 0};
        ushort4 t4 = {thi, 0, 0, 0};
        ushort4 l4 = {tlo, 0, 0, 0};
        *(ushort4*)&Xh[r][16] = t4; *(ushort4*)&Xh[r][20] = z4;
        *(ushort4*)&Xh[r][24] = z4; *(ushort4*)&Xh[r][28] = z4;
        *(ushort4*)&Xl[r][16] = l4; *(ushort4*)&Xl[r][20] = z4;
        *(ushort4*)&Xl[r][24] = z4; *(ushort4*)&Xl[r][28] = z4;
        *(ushort4*)&Th[r][16] = z4; *(ushort4*)&Th[r][20] = z4;
        *(ushort4*)&Th[r][24] = z4; *(ushort4*)&Th[r][28] = z4;
        *(ushort4*)&Tl[r][16] = z4; *(ushort4*)&Tl[r][20] = z4;
        *(ushort4*)&Tl[r][24] = z4; *(ushort4*)&Tl[r][28] = z4;
    }
    #pragma unroll
    for (int i = 0; i < 8; ++i) {   // h: single bf16 plane, 2048 float4
        int idx = tid + i * BLOCK;
        int r = idx >> 5, c4 = (idx & 31) * 4;
        float4 v = *(const float4*)(h + (r0 + r) * CTX + c4);
        uint2 hv = { cvtpk((f32x2){ v.x, v.y }), cvtpk((f32x2){ v.z, v.w }) };
        *(uint2*)&Xh[r][32 + c4] = hv;
    }
    __syncthreads();   // B1: staging visible

    const f32x4 zf = {0.f, 0.f, 0.f, 0.f};

    // ------------- layer 1 (operand-swapped; 12 independent acc chains) -------------
    // thread owns Z[m = rt*16+l16][n = (wv*3+j)*16 + quad*4 + rg]
    f32x4 z[4][3], u[4][3];
    #pragma unroll
    for (int rt = 0; rt < 4; ++rt)
        #pragma unroll
        for (int j = 0; j < 3; ++j) { z[rt][j] = zf; u[rt][j] = zf; }

    // weight fragments loaded INSIDE the kc loop: 12 VGPR transient, not 60 live
    #pragma unroll
    for (int kc = 0; kc < 5; ++kc) {
        bf16x8 w0 = *(const bf16x8*)(Wt1 + ((wv * 3 + 0) * 16 + l16) * KP1 + kc * 32 + quad * 8);
        bf16x8 w1 = *(const bf16x8*)(Wt1 + ((wv * 3 + 1) * 16 + l16) * KP1 + kc * 32 + quad * 8);
        bf16x8 w2 = *(const bf16x8*)(Wt1 + ((wv * 3 + 2) * 16 + l16) * KP1 + kc * 32 + quad * 8);
        #pragma unroll
        for (int rt = 0; rt < 4; ++rt) {
            bf16x8 ah = *(const bf16x8*)&Xh[rt * 16 + l16][kc * 32 + quad * 8];
            z[rt][0] = MFMA(w0, ah, z[rt][0]);
            z[rt][1] = MFMA(w1, ah, z[rt][1]);
            z[rt][2] = MFMA(w2, ah, z[rt][2]);
        }
    }
    {   // chunk-0 lo + tangent hi/lo (reload kc=0 fragments)
        bf16x8 w0 = *(const bf16x8*)(Wt1 + ((wv * 3 + 0) * 16 + l16) * KP1 + quad * 8);
        bf16x8 w1 = *(const bf16x8*)(Wt1 + ((wv * 3 + 1) * 16 + l16) * KP1 + quad * 8);
        bf16x8 w2 = *(const bf16x8*)(Wt1 + ((wv * 3 + 2) * 16 + l16) * KP1 + quad * 8);
        #pragma unroll
        for (int rt = 0; rt < 4; ++rt) {
            int m = rt * 16 + l16;
            bf16x8 al = *(const bf16x8*)&Xl[m][quad * 8];
            bf16x8 th = *(const bf16x8*)&Th[m][quad * 8];
            bf16x8 tl = *(const bf16x8*)&Tl[m][quad * 8];
            z[rt][0] = MFMA(w0, al, z[rt][0]);
            z[rt][1] = MFMA(w1, al, z[rt][1]);
            z[rt][2] = MFMA(w2, al, z[rt][2]);
            u[rt][0] = MFMA(w0, th, u[rt][0]);
            u[rt][1] = MFMA(w1, th, u[rt][1]);
            u[rt][2] = MFMA(w2, th, u[rt][2]);
            u[rt][0] = MFMA(w0, tl, u[rt][0]);
            u[rt][1] = MFMA(w1, tl, u[rt][1]);
            u[rt][2] = MFMA(w2, tl, u[rt][2]);
        }
    }
    // A/U alias the staging buffers: all waves' L1 LDS reads must complete
    // before epilogue-1 writes.
    __syncthreads();   // B2
    // epilogue 1: paired gelu + paired cvt; uint2 (8B) LDS stores
    #pragma unroll
    for (int j = 0; j < 3; ++j) {
        int n4 = (wv * 3 + j) * 16 + quad * 4;
        f32x4 bb4 = *(const f32x4*)(b1 + n4);
        #pragma unroll
        for (int rt = 0; rt < 4; ++rt) {
            int m = rt * 16 + l16;
            f32x2 x01 = { z[rt][j][0] + bb4[0], z[rt][j][1] + bb4[1] };
            f32x2 x23 = { z[rt][j][2] + bb4[2], z[rt][j][3] + bb4[3] };
            f32x2 a01, gp01, a23, gp23;
            gelu_pair2(x01, a01, gp01);
            gelu_pair2(x23, a23, gp23);
            f32x2 u01 = { u[rt][j][0], u[rt][j][1] };
            f32x2 u23 = { u[rt][j][2], u[rt][j][3] };
            uint2 apk = { cvtpk(a01), cvtpk(a23) };
            uint2 upk = { cvtpk(u01 * gp01), cvtpk(u23 * gp23) };
            *(uint2*)&A[m][n4] = apk;
            *(uint2*)&U[m][n4] = upk;
        }
    }
    __syncthreads();   // B3: A/U visible

    // ------------- layer 2 (operand-swapped; 24 acc chains) -------------
    f32x4 z2[4][3], u2[4][3];
    #pragma unroll
    for (int rt = 0; rt < 4; ++rt)
        #pragma unroll
        for (int j = 0; j < 3; ++j) { z2[rt][j] = zf; u2[rt][j] = zf; }

    #pragma unroll
    for (int kc = 0; kc < 6; ++kc) {
        bf16x8 w0 = *(const bf16x8*)(Wt2 + ((wv * 3 + 0) * 16 + l16) * H + kc * 32 + quad * 8);
        bf16x8 w1 = *(const bf16x8*)(Wt2 + ((wv * 3 + 1) * 16 + l16) * H + kc * 32 + quad * 8);
        bf16x8 w2 = *(const bf16x8*)(Wt2 + ((wv * 3 + 2) * 16 + l16) * H + kc * 32 + quad * 8);
        #pragma unroll
        for (int rt = 0; rt < 4; ++rt) {
            int m = rt * 16 + l16, o = kc * 32 + quad * 8;
            bf16x8 av = *(const bf16x8*)&A[m][o];
            bf16x8 uv = *(const bf16x8*)&U[m][o];
            z2[rt][0] = MFMA(w0, av, z2[rt][0]);
            z2[rt][1] = MFMA(w1, av, z2[rt][1]);
            z2[rt][2] = MFMA(w2, av, z2[rt][2]);
            u2[rt][0] = MFMA(w0, uv, u2[rt][0]);
            u2[rt][1] = MFMA(w1, uv, u2[rt][1]);
            u2[rt][2] = MFMA(w2, uv, u2[rt][2]);
        }
    }
    __syncthreads();   // B4: all A/U reads done before overwrite
    #pragma unroll
    for (int j = 0; j < 3; ++j) {
        int n4 = (wv * 3 + j) * 16 + quad * 4;
        f32x4 bb4 = *(const f32x4*)(b2 + n4);
        #pragma unroll
        for (int rt = 0; rt < 4; ++rt) {
            int m = rt * 16 + l16;
            f32x2 x01 = { z2[rt][j][0] + bb4[0], z2[rt][j][1] + bb4[1] };
            f32x2 x23 = { z2[rt][j][2] + bb4[2], z2[rt][j][3] + bb4[3] };
            f32x2 a01, gp01, a23, gp23;
            gelu_pair2(x01, a01, gp01);
            gelu_pair2(x23, a23, gp23);
            f32x2 u01 = { u2[rt][j][0], u2[rt][j][1] };
            f32x2 u23 = { u2[rt][j][2], u2[rt][j][3] };
            uint2 apk = { cvtpk(a01), cvtpk(a23) };
            uint2 upk = { cvtpk(u01 * gp01), cvtpk(u23 * gp23) };
            *(uint2*)&A[m][n4] = apk;
            *(uint2*)&U[m][n4] = upk;
        }
    }
    __syncthreads();   // B5: epi2 A/U visible

    // ------------- layer 3 + outputs (operand-swapped) -------------
    // wave: strm = wv&1 (value/tangent), row-tiles (wv>>1) and (wv>>1)+2
    {
        const int strm = wv & 1;
        const int r3a = wv >> 1, r3b = (wv >> 1) + 2;
        const unsigned short (*P)[200] = strm ? U : A;

        f32x4 acc_a = zf, acc_b = zf;
        #pragma unroll
        for (int kc = 0; kc < 6; ++kc) {
            bf16x8 wf = *(const bf16x8*)(Wt3 + l16 * H + kc * 32 + quad * 8);
            bf16x8 xa = *(const bf16x8*)&P[r3a * 16 + l16][kc * 32 + quad * 8];
            bf16x8 xb = *(const bf16x8*)&P[r3b * 16 + l16][kc * 32 + quad * 8];
            acc_a = MFMA(wf, xa, acc_a);
            acc_b = MFMA(wf, xb, acc_b);
        }

        const int ma = r3a * 16 + l16, mb = r3b * 16 + l16;
        if (strm == 0) {
            f32x4 bb4 = *(const f32x4*)(b3 + quad * 4);
            f32x4 oa = acc_a + bb4;
            f32x4 ob = acc_b + bb4;
            *(f32x4*)(out_f + (r0 + ma) * D + quad * 4) = oa;
            *(f32x4*)(out_f + (r0 + mb) * D + quad * 4) = ob;
        } else {
            f32x4 ea = *(const f32x4*)(eps + (r0 + ma) * D + quad * 4);
            f32x4 eb = *(const f32x4*)(eps + (r0 + mb) * D + quad * 4);
            float pa = acc_a[0] * ea[0] + acc_a[1] * ea[1] + acc_a[2] * ea[2] + acc_a[3] * ea[3];
            float pb = acc_b[0] * eb[0] + acc_b[1] * eb[1] + acc_b[2] * eb[2] + acc_b[3] * eb[3];
            pa += __shfl_xor(pa, 16, 64);
            pa += __shfl_xor(pa, 32, 64);
            pb += __shfl_xor(pb, 16, 64);
            pb += __shfl_xor(pb, 32, 64);
            if (quad == 0) {
                out_dlogp[r0 + ma] = -pa;
                out_dlogp[r0 + mb] = -pb;
            }
        }
    }
}

extern "C" void kernel_launch(void* const* d_in, const int* in_sizes, int n_in,
                              void* d_out, int out_size, void* d_ws, size_t ws_size,
                              hipStream_t stream)
{
    const float* t   = (const float*)d_in[0];
    const float* y   = (const float*)d_in[1];
    const float* h   = (const float*)d_in[3];
    const float* eps = (const float*)d_in[4];
    const float* W1  = (const float*)d_in[5];
    const float* b1  = (const float*)d_in[6];
    const float* W2  = (const float*)d_in[7];
    const float* b2  = (const float*)d_in[8];
    const float* W3  = (const float*)d_in[9];
    const float* b3  = (const float*)d_in[10];

    float* out       = (float*)d_out;
    float* out_f     = out;
    float* out_dlogp = out + (size_t)B_TOTAL * D;
    float* out_dh    = out + (size_t)B_TOTAL * (D + 1);

    unsigned short* wt = (unsigned short*)d_ws;

    int prep_elems = H * KP1 + H * H + D * H;   // 70656
    prep_weights<<<(prep_elems + 255) / 256, 256, 0, stream>>>(W1, W2, W3, wt);

    odefunc_mfma<<<B_TOTAL / M, BLOCK, 0, stream>>>(
        t, y, h, eps, b1, b2, b3, wt, out_f, out_dlogp, out_dh);
}